// Round 11
// baseline (316.285 us; speedup 1.0000x reference)
//
#include <hip/hip_runtime.h>
#include <hip/hip_bf16.h>
#include <hip/hip_cooperative_groups.h>

#define HD   64
#define SEQ  2048
#define NB   256
#define TWOH 128
#define NCH  32   // SEQ / 64

typedef float v4f __attribute__((ext_vector_type(4)));

// ws float layout:
// [0,4096)      k_tab  (normalized k per token)
// [4096,8192)   v_tab
// [8192,12288)  q_tab
// [12288,12352) thr2   ((0.4*||v_t||)^2)
#define WS_V    4096
#define WS_Q    8192
#define WS_THR  12288

// ---- DPP wave-total: sum across 64 lanes, broadcast via lane 63 ----
template <int CTRL>
__device__ __forceinline__ float dpp_add(float x) {
    int y = __builtin_amdgcn_update_dpp(0, __builtin_bit_cast(int, x),
                                        CTRL, 0xF, 0xF, true);
    return x + __builtin_bit_cast(float, y);
}

__device__ __forceinline__ float wave_total(float x) {
    x = dpp_add<0x111>(x);   // row_shr:1
    x = dpp_add<0x112>(x);   // row_shr:2
    x = dpp_add<0x114>(x);   // row_shr:4
    x = dpp_add<0x118>(x);   // row_shr:8
    x = dpp_add<0x142>(x);   // row_bcast:15
    x = dpp_add<0x143>(x);   // row_bcast:31 -> lane 63 has full sum
    return __builtin_bit_cast(float,
        __builtin_amdgcn_readlane(__builtin_bit_cast(int, x), 63));
}

__device__ __forceinline__ float bcastf(float v, int l) {
    return __builtin_bit_cast(float,
        __builtin_amdgcn_readlane(__builtin_bit_cast(int, v), l));
}

__device__ __forceinline__ float hsum4(v4f a) {
    return (a.x + a.y) + (a.z + a.w);
}

// f32 data read as bf16 at even 16-bit halves -> huge/NaN values. Wave-level
// (__any over 64 lanes); lane-indexed so all waves get identical results.
__device__ __forceinline__ bool detect_bf16(const void* embed, int lane) {
    const unsigned short* u = (const unsigned short*)embed;
    int bad = 0;
    for (int i = 2 * lane; i < 4096; i += 128) {
        float v = __uint_as_float(((unsigned int)u[i]) << 16);
        if (!(fabsf(v) < 1e4f)) bad = 1;
    }
    return !__any(bad);
}

template <bool BF>
__device__ __forceinline__ float ldf(const void* p, int i) {
    if (BF) return __bfloat162float(((const __hip_bfloat16*)p)[i]);
    return ((const float*)p)[i];
}

#define LGKM_BARRIER() asm volatile("s_waitcnt lgkmcnt(0)" ::: "memory")

// Single-wave encoder for one token (R5-verified math; __syncthreads replaced
// by same-wave DS-order + lgkmcnt/"memory" fences, the R9/R10-proven pattern).
// Runs on wave 0 of blocks 0..63 (token = blockIdx.x), 64-CU parallel.
template <bool BF>
__device__ void encode1(int t, int lane, const void* embed, const void* w1,
                        const void* b1, const void* w2, const void* b2,
                        const void* ln_g, const void* ln_b, const void* wk,
                        const void* wvp, const void* wq, float* __restrict__ ws,
                        float* __restrict__ shh, float* __restrict__ shu) {
    float h = ldf<BF>(embed, t * HD + lane);
    shh[lane] = h;
    LGKM_BARRIER();

    // FFN1: u = relu(h @ w1 + b1); lane -> outputs (lane, lane+64)
    float a0 = 0.f, a1 = 0.f, a2 = 0.f, a3 = 0.f;
    #pragma unroll 16
    for (int j = 0; j < HD; j += 2) {
        float h0 = shh[j], h1 = shh[j + 1];
        a0 = fmaf(h0, ldf<BF>(w1, j * TWOH + lane), a0);
        a1 = fmaf(h0, ldf<BF>(w1, j * TWOH + lane + HD), a1);
        a2 = fmaf(h1, ldf<BF>(w1, (j + 1) * TWOH + lane), a2);
        a3 = fmaf(h1, ldf<BF>(w1, (j + 1) * TWOH + lane + HD), a3);
    }
    shu[lane]      = fmaxf(a0 + a2 + ldf<BF>(b1, lane), 0.f);
    shu[lane + HD] = fmaxf(a1 + a3 + ldf<BF>(b1, lane + HD), 0.f);
    LGKM_BARRIER();

    // FFN2 + residual
    float f0 = 0.f, f1 = 0.f, f2 = 0.f, f3 = 0.f;
    #pragma unroll 16
    for (int e = 0; e < TWOH; e += 4) {
        f0 = fmaf(shu[e + 0], ldf<BF>(w2, (e + 0) * HD + lane), f0);
        f1 = fmaf(shu[e + 1], ldf<BF>(w2, (e + 1) * HD + lane), f1);
        f2 = fmaf(shu[e + 2], ldf<BF>(w2, (e + 2) * HD + lane), f2);
        f3 = fmaf(shu[e + 3], ldf<BF>(w2, (e + 3) * HD + lane), f3);
    }
    float y = h + (f0 + f1) + (f2 + f3) + ldf<BF>(b2, lane);

    // LayerNorm over 64 dims (eps 1e-5)
    float mu  = wave_total(y) * 0.015625f;
    float dvv = y - mu;
    float var = wave_total(dvv * dvv) * 0.015625f;
    float hn  = fmaf(dvv * (1.f / sqrtf(var + 1e-5f)), ldf<BF>(ln_g, lane),
                     ldf<BF>(ln_b, lane));

    LGKM_BARRIER();                          // FFN1's shh reads complete
    shh[lane] = hn;
    LGKM_BARRIER();

    // k/v/q projections
    float k0 = 0.f, k1 = 0.f, v0 = 0.f, v1 = 0.f, q0 = 0.f, q1 = 0.f;
    #pragma unroll 16
    for (int j = 0; j < HD; j += 2) {
        float h0 = shh[j], h1 = shh[j + 1];
        k0 = fmaf(h0, ldf<BF>(wk, j * HD + lane), k0);
        v0 = fmaf(h0, ldf<BF>(wvp, j * HD + lane), v0);
        q0 = fmaf(h0, ldf<BF>(wq, j * HD + lane), q0);
        k1 = fmaf(h1, ldf<BF>(wk, (j + 1) * HD + lane), k1);
        v1 = fmaf(h1, ldf<BF>(wvp, (j + 1) * HD + lane), v1);
        q1 = fmaf(h1, ldf<BF>(wq, (j + 1) * HD + lane), q1);
    }
    float k = k0 + k1, v = v0 + v1, q = q0 + q1;
    float nk = sqrtf(wave_total(k * k));
    k /= fmaxf(nk, 1e-12f);                  // k / max(||k||, NORM_EPS)
    float nv2 = wave_total(v * v);

    ws[t * HD + lane]        = k;
    ws[WS_V + t * HD + lane] = v;
    ws[WS_Q + t * HD + lane] = q;
    if (lane == 0) ws[WS_THR + t] = 0.16f * nv2;   // (0.4*||v||)^2
}

// Cooperative single dispatch: 256 blocks x 256 threads.
// Pre-sync: every block stages its token stream; blocks 0..63 (wave 0)
// encode token b into global ws in parallel. grid.sync() (device-scope).
// Post-sync: R8-verified scan — wave w owns components [16w,16w+16) of every
// token's residual dv; fires broadcast delta quarters from own-lane registers
// (16 readlanes), 12 pk_fma, combine ||dv||^2 partials via ping-pong LDS with
// ONE barrier per fire.
__global__ __launch_bounds__(256, 1) void fused_kernel(
    const int* __restrict__ x, const void* embed, const void* w1,
    const void* b1, const void* w2, const void* b2, const void* ln_g,
    const void* ln_b, const void* wk, const void* wvp, const void* wq,
    const void* wo, const void* bo, float* __restrict__ ws,
    void* __restrict__ out) {
    const int b = blockIdx.x, tid = threadIdx.x;
    const int wid = tid >> 6, lane = tid & 63;
    __shared__ __align__(16) float k_lds[4096];
    __shared__ __align__(16) float g_lds[4096];
    __shared__ int   tok_lds[SEQ];
    __shared__ float pbuf[2][4][64];     // ping-pong nd2 partials
    __shared__ __align__(16) float rd_lds[64];
    __shared__ float enc_h[HD];          // encoder scratch (wave 0 only)
    __shared__ float enc_u[TWOH];

    // stage token stream (coalesced over 256 threads) — independent of ws
    const int* xr = x + b * SEQ;
    #pragma unroll
    for (int c = 0; c < 8; ++c) tok_lds[c * 256 + tid] = xr[c * 256 + tid];
    const int tl = xr[SEQ - 1];

    const bool bf = detect_bf16(embed, lane);

    // Phase 1: parallel encoder (blocks 0..63, wave 0 only; no block barriers)
    if (b < 64 && wid == 0) {
        if (bf)
            encode1<true>(b, lane, embed, w1, b1, w2, b2, ln_g, ln_b,
                          wk, wvp, wq, ws, enc_h, enc_u);
        else
            encode1<false>(b, lane, embed, w1, b1, w2, b2, ln_g, ln_b,
                           wk, wvp, wq, ws, enc_h, enc_u);
        __threadfence();                 // device-scope release of ws writes
    }
    cooperative_groups::this_grid().sync();

    // ---- Phase 2: R8-verified scan ----
    // stage K into LDS (coalesced)
    #pragma unroll
    for (int i = 0; i < 4; ++i) {
        int o = i * 1024 + tid * 4;
        *(float4*)&k_lds[o] = *(const float4*)&ws[o];
    }
    const float thr2 = ws[WS_THR + lane];

    // k_lane full row into registers (global, L2-hot; identical across waves)
    v4f kreg[16];
    const float* krow = ws + lane * HD;
    #pragma unroll
    for (int i = 0; i < 16; ++i) {
        float4 kv = *(const float4*)&krow[i * 4];
        kreg[i] = (v4f){kv.x, kv.y, kv.z, kv.w};
    }
    // cq_lane = k_lane . q_{last token}
    const float* qrow = ws + WS_Q + tl * HD;
    v4f cacc = {0.f, 0.f, 0.f, 0.f};
    #pragma unroll
    for (int i = 0; i < 16; ++i) {
        const float* qp = &qrow[i * 4];
        v4f qv = {qp[0], qp[1], qp[2], qp[3]};
        cacc = __builtin_elementwise_fma(qv, kreg[i], cacc);
    }
    const float cq = hsum4(cacc);
    __syncthreads();                       // k_lds visible

    // G build: wave w computes rows [16w,16w+16): G[t][lane] = k_t . k_lane
    #pragma unroll 1
    for (int t0 = 0; t0 < 16; ++t0) {
        const int t = wid * 16 + t0;
        const float* kt = &k_lds[t * HD];    // uniform -> LDS broadcast
        v4f a = {0.f, 0.f, 0.f, 0.f};
        #pragma unroll
        for (int i = 0; i < 16; ++i) {
            const v4f kv = *(const v4f*)&kt[i * 4];
            a = __builtin_elementwise_fma(kv, kreg[i], a);
        }
        g_lds[t * HD + lane] = hsum4(a);
    }

    // dv quarter = v_lane[16wid..16wid+16); R = 0; partial nd2
    v4f dv[4], R[4];
    const float* vr = ws + WS_V + lane * HD + wid * 16;
    v4f acc = {0.f, 0.f, 0.f, 0.f};
    #pragma unroll
    for (int i = 0; i < 4; ++i) {
        float4 vvv = *(const float4*)&vr[i * 4];
        dv[i] = (v4f){vvv.x, vvv.y, vvv.z, vvv.w};
        R[i]  = (v4f){0.f, 0.f, 0.f, 0.f};
        acc   = __builtin_elementwise_fma(dv[i], dv[i], acc);
    }
    pbuf[0][wid][lane] = hsum4(acc);
    int pp = 1;
    __syncthreads();                       // g_lds + pbuf[0] visible
    float nd2 = ((pbuf[0][0][lane] + pbuf[0][1][lane]) +
                 (pbuf[0][2][lane] + pbuf[0][3][lane]));
    unsigned long long fireset = __ballot(nd2 > thr2);

    // fire loop
    int chunk = tok_lds[lane];
    #pragma unroll 1
    for (int c = 0; c < NCH; ++c) {
        int nxt = 0;
        if (c + 1 < NCH) nxt = tok_lds[(c + 1) * 64 + lane];
        unsigned long long pend = __ballot((int)((fireset >> chunk) & 1ull));
        while (pend) {
            const int s = __builtin_ctzll(pend);
            const int t = __builtin_amdgcn_readlane(chunk, s);
            const float g   = g_lds[t * HD + lane];
            const float cqt = bcastf(cq, t);
            const v4f gs  = {-g, -g, -g, -g};
            const v4f cqs = {cqt, cqt, cqt, cqt};
            v4f q4 = {0.f, 0.f, 0.f, 0.f};
            #pragma unroll
            for (int i = 0; i < 4; ++i) {
                v4f sve;                           // delta_t quarter (own regs)
                sve.x = bcastf(dv[i].x, t);
                sve.y = bcastf(dv[i].y, t);
                sve.z = bcastf(dv[i].z, t);
                sve.w = bcastf(dv[i].w, t);
                dv[i] = __builtin_elementwise_fma(gs, sve, dv[i]);
                R[i]  = __builtin_elementwise_fma(cqs, sve, R[i]);
                q4    = __builtin_elementwise_fma(dv[i], dv[i], q4);
            }
            pbuf[pp][wid][lane] = hsum4(q4);
            __syncthreads();                       // single barrier per fire
            nd2 = ((pbuf[pp][0][lane] + pbuf[pp][1][lane]) +
                   (pbuf[pp][2][lane] + pbuf[pp][3][lane]));
            pp ^= 1;                               // ping-pong: no 2nd barrier
            fireset = __ballot(nd2 > thr2);
            const unsigned long long above =
                (s >= 63) ? 0ull : (~0ull << (s + 1));
            pend = __ballot((int)((fireset >> chunk) & 1ull)) & above;
        }
        chunk = nxt;
    }

    // read = relu(R): wave w holds components [16wid..16wid+16) in each lane
    if (lane == 0) {
        #pragma unroll
        for (int i = 0; i < 4; ++i) {
            v4f r = R[i];
            r.x = fmaxf(r.x, 0.f); r.y = fmaxf(r.y, 0.f);
            r.z = fmaxf(r.z, 0.f); r.w = fmaxf(r.w, 0.f);
            *(v4f*)&rd_lds[wid * 16 + i * 4] = r;
        }
    }
    __syncthreads();

    // out[b][c] = sum_j rd[j] * wo[j][c] + bo[c]  — wave 0 only (lane = c)
    if (wid == 0) {
        if (bf) {
            float acc2 = __bfloat162float(((const __hip_bfloat16*)bo)[lane]);
            #pragma unroll 8
            for (int j = 0; j < HD; ++j)
                acc2 = fmaf(rd_lds[j],
                    __bfloat162float(((const __hip_bfloat16*)wo)[j * HD + lane]),
                    acc2);
            ((__hip_bfloat16*)out)[b * HD + lane] = __float2bfloat16(acc2);
        } else {
            float acc2 = ((const float*)bo)[lane];
            #pragma unroll 8
            for (int j = 0; j < HD; ++j)
                acc2 = fmaf(rd_lds[j], ((const float*)wo)[j * HD + lane], acc2);
            ((float*)out)[b * HD + lane] = acc2;
        }
    }
}

extern "C" void kernel_launch(void* const* d_in, const int* in_sizes, int n_in,
                              void* d_out, int out_size, void* d_ws, size_t ws_size,
                              hipStream_t stream) {
    const int* x      = (const int*)d_in[0];
    const void* embed = d_in[1];
    const void* w1    = d_in[2];
    const void* b1    = d_in[3];
    const void* w2    = d_in[4];
    const void* b2    = d_in[5];
    const void* ln_g  = d_in[6];
    const void* ln_b  = d_in[7];
    const void* wk    = d_in[8];
    const void* wvp   = d_in[9];
    const void* wq    = d_in[10];
    const void* wo    = d_in[11];
    const void* bo    = d_in[12];
    float* ws = (float*)d_ws;
    void* outp = d_out;

    void* kargs[] = {
        (void*)&x, (void*)&embed, (void*)&w1, (void*)&b1, (void*)&w2,
        (void*)&b2, (void*)&ln_g, (void*)&ln_b, (void*)&wk, (void*)&wvp,
        (void*)&wq, (void*)&wo, (void*)&bo, (void*)&ws, (void*)&outp};
    hipLaunchCooperativeKernel((const void*)fused_kernel, dim3(NB), dim3(256),
                               kargs, 0, stream);
}

// Round 13
// 306.937 us; speedup vs baseline: 1.0305x; 1.0305x over previous
//
#include <hip/hip_runtime.h>
#include <hip/hip_bf16.h>

#define HD   64
#define SEQ  2048
#define NB   256
#define TWOH 128
#define NCH  32   // SEQ / 64

typedef float v4f __attribute__((ext_vector_type(4)));

// ---- DPP wave-total: sum across 64 lanes, broadcast via lane 63 ----
template <int CTRL>
__device__ __forceinline__ float dpp_add(float x) {
    int y = __builtin_amdgcn_update_dpp(0, __builtin_bit_cast(int, x),
                                        CTRL, 0xF, 0xF, true);
    return x + __builtin_bit_cast(float, y);
}

__device__ __forceinline__ float wave_total(float x) {
    x = dpp_add<0x111>(x);   // row_shr:1
    x = dpp_add<0x112>(x);   // row_shr:2
    x = dpp_add<0x114>(x);   // row_shr:4
    x = dpp_add<0x118>(x);   // row_shr:8
    x = dpp_add<0x142>(x);   // row_bcast:15
    x = dpp_add<0x143>(x);   // row_bcast:31 -> lane 63 has full sum
    return __builtin_bit_cast(float,
        __builtin_amdgcn_readlane(__builtin_bit_cast(int, x), 63));
}

__device__ __forceinline__ float bcastf(float v, int l) {
    return __builtin_bit_cast(float,
        __builtin_amdgcn_readlane(__builtin_bit_cast(int, v), l));
}

__device__ __forceinline__ float hsum4(v4f a) {
    return (a.x + a.y) + (a.z + a.w);
}

// f32 data read as bf16 at even 16-bit halves -> huge/NaN values. Wave-level
// (__any over 64 lanes); lane-indexed so all waves get identical results.
__device__ __forceinline__ bool detect_bf16(const void* embed, int lane) {
    const unsigned short* u = (const unsigned short*)embed;
    int bad = 0;
    for (int i = 2 * lane; i < 4096; i += 128) {
        float v = __uint_as_float(((unsigned int)u[i]) << 16);
        if (!(fabsf(v) < 1e4f)) bad = 1;
    }
    return !__any(bad);
}

template <bool BF>
__device__ __forceinline__ float ldf(const void* p, int i) {
    if (BF) return __bfloat162float(((const __hip_bfloat16*)p)[i]);
    return ((const float*)p)[i];
}

#define LGKM_BARRIER() asm volatile("s_waitcnt lgkmcnt(0)" ::: "memory")

// Stage weights into LDS (coalesced over 256 threads), then weight-streaming
// encode: wave `wid` encodes tokens 16wid..16wid+16 simultaneously (token dim
// in registers, feature dim in lanes), reading weights from LDS (ds_read ~6cyc
// throughput — kills R10's ~30 µs of exposed global-load latency) with
// next-iteration software prefetch. q computed only for token tl (global wq,
// fully-unrolled loads). Encoder h/u scratch aliases k/v tables (writes occur
// strictly after last scratch reads; same-wave order + lgkmcnt fences — R4).
template <bool BF>
__device__ void stage_and_encode(int tid, int wid, int lane, int tl,
                                 const void* embed, const void* w1,
                                 const void* b1, const void* w2, const void* b2,
                                 const void* ln_g, const void* ln_b,
                                 const void* wk, const void* wvp, const void* wq,
                                 float* __restrict__ w1_lds,
                                 float* __restrict__ w2_lds,
                                 float* __restrict__ wk_lds,
                                 float* __restrict__ wv_lds,
                                 float* __restrict__ k_lds,
                                 float* __restrict__ v_lds,
                                 float* __restrict__ thr2_lds,
                                 float* __restrict__ qrow_s) {
    // ---- weight staging (all 256 threads) ----
    #pragma unroll 8
    for (int i = tid; i < 8192; i += 256) w1_lds[i] = ldf<BF>(w1, i);
    #pragma unroll 8
    for (int i = tid; i < 8192; i += 256) w2_lds[i] = ldf<BF>(w2, i);
    #pragma unroll 8
    for (int i = tid; i < 4096; i += 256) wk_lds[i] = ldf<BF>(wk, i);
    #pragma unroll 8
    for (int i = tid; i < 4096; i += 256) wv_lds[i] = ldf<BF>(wvp, i);
    __syncthreads();

    const int tbase = wid * 16;
    float* hb = &k_lds[wid * 1024];      // alias: overwritten by k at the end
    float* ub = &v_lds[wid * 1024];      // alias: overwritten by v at the end

    float h[16];
    #pragma unroll
    for (int it = 0; it < 16; ++it) {
        h[it] = ldf<BF>(embed, (tbase + it) * HD + lane);
        hb[it * HD + lane] = h[it];
    }
    LGKM_BARRIER();

    // FFN1: u[it][e] = relu(sum_j h[it][j]*w1[j][e] + b1[e]); e = lane,lane+64
    float u0[16], u1[16];
    #pragma unroll
    for (int it = 0; it < 16; ++it) { u0[it] = 0.f; u1[it] = 0.f; }
    float a0 = w1_lds[0 * TWOH + lane], b0 = w1_lds[0 * TWOH + lane + HD];
    float a1 = w1_lds[1 * TWOH + lane], b1w = w1_lds[1 * TWOH + lane + HD];
    float a2 = w1_lds[2 * TWOH + lane], b2w = w1_lds[2 * TWOH + lane + HD];
    float a3 = w1_lds[3 * TWOH + lane], b3w = w1_lds[3 * TWOH + lane + HD];
    #pragma unroll 1
    for (int j4 = 0; j4 < 16; ++j4) {
        float na0 = 0, nb0 = 0, na1 = 0, nb1 = 0,
              na2 = 0, nb2 = 0, na3 = 0, nb3 = 0;
        if (j4 < 15) {                       // prefetch next rows
            const int j = (j4 + 1) * 4;
            na0 = w1_lds[(j + 0) * TWOH + lane];
            nb0 = w1_lds[(j + 0) * TWOH + lane + HD];
            na1 = w1_lds[(j + 1) * TWOH + lane];
            nb1 = w1_lds[(j + 1) * TWOH + lane + HD];
            na2 = w1_lds[(j + 2) * TWOH + lane];
            nb2 = w1_lds[(j + 2) * TWOH + lane + HD];
            na3 = w1_lds[(j + 3) * TWOH + lane];
            nb3 = w1_lds[(j + 3) * TWOH + lane + HD];
        }
        const int j = j4 * 4;
        #pragma unroll
        for (int it = 0; it < 16; ++it) {
            const v4f hj = *(const v4f*)&hb[it * HD + j];   // uniform bcast
            u0[it] = fmaf(hj.x, a0, u0[it]); u1[it] = fmaf(hj.x, b0, u1[it]);
            u0[it] = fmaf(hj.y, a1, u0[it]); u1[it] = fmaf(hj.y, b1w, u1[it]);
            u0[it] = fmaf(hj.z, a2, u0[it]); u1[it] = fmaf(hj.z, b2w, u1[it]);
            u0[it] = fmaf(hj.w, a3, u0[it]); u1[it] = fmaf(hj.w, b3w, u1[it]);
        }
        a0 = na0; b0 = nb0; a1 = na1; b1w = nb1;
        a2 = na2; b2w = nb2; a3 = na3; b3w = nb3;
    }
    const float bb0 = ldf<BF>(b1, lane), bb1 = ldf<BF>(b1, lane + HD);
    #pragma unroll
    for (int it = 0; it < 16; ++it) {
        u0[it] = fmaxf(u0[it] + bb0, 0.f);
        u1[it] = fmaxf(u1[it] + bb1, 0.f);
    }

    // FFN2 (two e-passes through ub)
    float f[16];
    #pragma unroll
    for (int it = 0; it < 16; ++it) f[it] = 0.f;
    #pragma unroll
    for (int it = 0; it < 16; ++it) ub[it * HD + lane] = u0[it];
    LGKM_BARRIER();
    #pragma unroll 1
    for (int pass = 0; pass < 2; ++pass) {
        const int ebase = pass * HD;
        float w0 = w2_lds[(ebase + 0) * HD + lane];
        float w1v = w2_lds[(ebase + 1) * HD + lane];
        float w2v = w2_lds[(ebase + 2) * HD + lane];
        float w3 = w2_lds[(ebase + 3) * HD + lane];
        #pragma unroll 1
        for (int e4 = 0; e4 < 16; ++e4) {
            float n0 = 0, n1 = 0, n2 = 0, n3 = 0;
            if (e4 < 15) {
                const int e = ebase + (e4 + 1) * 4;
                n0 = w2_lds[(e + 0) * HD + lane];
                n1 = w2_lds[(e + 1) * HD + lane];
                n2 = w2_lds[(e + 2) * HD + lane];
                n3 = w2_lds[(e + 3) * HD + lane];
            }
            const int e = e4 * 4;
            #pragma unroll
            for (int it = 0; it < 16; ++it) {
                const v4f ue = *(const v4f*)&ub[it * HD + e];  // uniform bcast
                f[it] = fmaf(ue.x, w0, f[it]);
                f[it] = fmaf(ue.y, w1v, f[it]);
                f[it] = fmaf(ue.z, w2v, f[it]);
                f[it] = fmaf(ue.w, w3, f[it]);
            }
            w0 = n0; w1v = n1; w2v = n2; w3 = n3;
        }
        if (pass == 0) {                     // swap in u1 for the second pass
            LGKM_BARRIER();                  // pass-0 ub reads complete
            #pragma unroll
            for (int it = 0; it < 16; ++it) ub[it * HD + lane] = u1[it];
            LGKM_BARRIER();
        }
    }
    const float b2v = ldf<BF>(b2, lane);
    const float lg = ldf<BF>(ln_g, lane), lb = ldf<BF>(ln_b, lane);

    // LayerNorm per token + restage hn into hb
    LGKM_BARRIER();                          // all hb FFN1 reads complete
    #pragma unroll 1
    for (int it = 0; it < 16; ++it) {
        float y = h[it] + f[it] + b2v;
        float mu  = wave_total(y) * 0.015625f;
        float dvv = y - mu;
        float var = wave_total(dvv * dvv) * 0.015625f;
        float hn  = fmaf(dvv * (1.f / sqrtf(var + 1e-5f)), lg, lb);
        hb[it * HD + lane] = hn;
    }
    LGKM_BARRIER();

    // k/v projections (streamed from LDS, prefetched)
    float k[16], v[16];
    #pragma unroll
    for (int it = 0; it < 16; ++it) { k[it] = 0.f; v[it] = 0.f; }
    float ka = wk_lds[0 * HD + lane], kb = wk_lds[1 * HD + lane];
    float kc = wk_lds[2 * HD + lane], kd = wk_lds[3 * HD + lane];
    float va = wv_lds[0 * HD + lane], vb = wv_lds[1 * HD + lane];
    float vc = wv_lds[2 * HD + lane], vd = wv_lds[3 * HD + lane];
    #pragma unroll 1
    for (int j4 = 0; j4 < 16; ++j4) {
        float nka = 0, nkb = 0, nkc = 0, nkd = 0,
              nva = 0, nvb = 0, nvc = 0, nvd = 0;
        if (j4 < 15) {
            const int j = (j4 + 1) * 4;
            nka = wk_lds[(j + 0) * HD + lane];
            nkb = wk_lds[(j + 1) * HD + lane];
            nkc = wk_lds[(j + 2) * HD + lane];
            nkd = wk_lds[(j + 3) * HD + lane];
            nva = wv_lds[(j + 0) * HD + lane];
            nvb = wv_lds[(j + 1) * HD + lane];
            nvc = wv_lds[(j + 2) * HD + lane];
            nvd = wv_lds[(j + 3) * HD + lane];
        }
        const int j = j4 * 4;
        #pragma unroll
        for (int it = 0; it < 16; ++it) {
            const v4f hj = *(const v4f*)&hb[it * HD + j];    // uniform bcast
            k[it] = fmaf(hj.x, ka, k[it]); v[it] = fmaf(hj.x, va, v[it]);
            k[it] = fmaf(hj.y, kb, k[it]); v[it] = fmaf(hj.y, vb, v[it]);
            k[it] = fmaf(hj.z, kc, k[it]); v[it] = fmaf(hj.z, vc, v[it]);
            k[it] = fmaf(hj.w, kd, k[it]); v[it] = fmaf(hj.w, vd, v[it]);
        }
        ka = nka; kb = nkb; kc = nkc; kd = nkd;
        va = nva; vb = nvb; vc = nvc; vd = nvd;
    }

    // q only for token tl (global wq, fully-unrolled loads — deep pipeline)
    if (tl >= tbase && tl < tbase + 16) {    // wave-uniform
        const int it = tl - tbase;
        float q = 0.f;
        #pragma unroll
        for (int j4 = 0; j4 < 16; ++j4) {
            const v4f hj = *(const v4f*)&hb[it * HD + j4 * 4];
            q = fmaf(hj.x, ldf<BF>(wq, (j4 * 4 + 0) * HD + lane), q);
            q = fmaf(hj.y, ldf<BF>(wq, (j4 * 4 + 1) * HD + lane), q);
            q = fmaf(hj.z, ldf<BF>(wq, (j4 * 4 + 2) * HD + lane), q);
            q = fmaf(hj.w, ldf<BF>(wq, (j4 * 4 + 3) * HD + lane), q);
        }
        qrow_s[lane] = q;
    }

    // normalize + write tables (overwrites hb/ub region — all reads done)
    LGKM_BARRIER();
    #pragma unroll 1
    for (int it = 0; it < 16; ++it) {
        const int t = tbase + it;
        float nk = sqrtf(wave_total(k[it] * k[it]));
        float kn = k[it] / fmaxf(nk, 1e-12f);       // k / max(||k||, NORM_EPS)
        float nv2 = wave_total(v[it] * v[it]);
        k_lds[t * HD + lane] = kn;
        v_lds[t * HD + lane] = v[it];
        if (lane == 0) thr2_lds[t] = 0.16f * nv2;   // (0.4*||v||)^2
    }
}

// Single plain launch (R11 showed cooperative costs ~2x launch overhead):
// 256 blocks x 4 waves. Phase 1: LDS-staged weights + streaming encoder.
// Phase 2: R8-verified fire loop — wave w owns components [16w,16w+16) of
// every token's residual dv; fires broadcast delta quarters from own-lane
// registers (16 readlanes), 12 pk_fma, combine ||dv||^2 partials via
// ping-pong LDS with ONE barrier per fire. G aliases the dead w1 region.
__global__ __launch_bounds__(256, 1) void fused_kernel(
    const int* __restrict__ x, const void* embed, const void* w1,
    const void* b1, const void* w2, const void* b2, const void* ln_g,
    const void* ln_b, const void* wk, const void* wvp, const void* wq,
    const void* wo, const void* bo, void* __restrict__ out) {
    const int b = blockIdx.x, tid = threadIdx.x;
    const int wid = tid >> 6, lane = tid & 63;
    __shared__ __align__(16) float w1_lds[8192];   // 32 KB; G aliases [0,4096)
    __shared__ __align__(16) float w2_lds[8192];   // 32 KB
    __shared__ __align__(16) float wk_lds[4096];   // 16 KB
    __shared__ __align__(16) float wv_lds[4096];   // 16 KB
    __shared__ __align__(16) float k_lds[4096];    // 16 KB; hb aliases per wave
    __shared__ __align__(16) float v_lds[4096];    // 16 KB; ub aliases per wave
    __shared__ int   tok_lds[SEQ];                 // 8 KB
    __shared__ float thr2_lds[64];
    __shared__ float qrow_s[64];
    __shared__ float pbuf[2][4][64];     // ping-pong nd2 partials
    __shared__ __align__(16) float rd_lds[64];

    // stage token stream (coalesced over 256 threads)
    const int* xr = x + b * SEQ;
    #pragma unroll
    for (int c = 0; c < 8; ++c) tok_lds[c * 256 + tid] = xr[c * 256 + tid];
    const int tl = xr[SEQ - 1];

    // Phase 1: encoder
    const bool bf = detect_bf16(embed, lane);
    if (bf)
        stage_and_encode<true>(tid, wid, lane, tl, embed, w1, b1, w2, b2,
                               ln_g, ln_b, wk, wvp, wq, w1_lds, w2_lds,
                               wk_lds, wv_lds, k_lds, v_lds, thr2_lds, qrow_s);
    else
        stage_and_encode<false>(tid, wid, lane, tl, embed, w1, b1, w2, b2,
                                ln_g, ln_b, wk, wvp, wq, w1_lds, w2_lds,
                                wk_lds, wv_lds, k_lds, v_lds, thr2_lds, qrow_s);
    __syncthreads();                     // tables visible; weights dead

    const float thr2 = thr2_lds[lane];
    float* g_lds = w1_lds;               // alias the dead w1 region

    // k_lane full row into registers (one-time; row-read conflicts accepted)
    v4f kreg[16];
    #pragma unroll
    for (int i = 0; i < 16; ++i)
        kreg[i] = *(const v4f*)&k_lds[lane * HD + i * 4];

    // cq_lane = k_lane . q_tl  (qrow_s uniform reads -> broadcast)
    v4f cacc = {0.f, 0.f, 0.f, 0.f};
    #pragma unroll
    for (int i = 0; i < 16; ++i) {
        const v4f qv = *(const v4f*)&qrow_s[i * 4];
        cacc = __builtin_elementwise_fma(qv, kreg[i], cacc);
    }
    const float cq = hsum4(cacc);

    // G build: wave w computes rows [16w,16w+16): G[t][lane] = k_t . k_lane
    #pragma unroll 1
    for (int t0 = 0; t0 < 16; ++t0) {
        const int t = wid * 16 + t0;
        const float* kt = &k_lds[t * HD];    // uniform -> LDS broadcast
        v4f a = {0.f, 0.f, 0.f, 0.f};
        #pragma unroll
        for (int i = 0; i < 16; ++i) {
            const v4f kv = *(const v4f*)&kt[i * 4];
            a = __builtin_elementwise_fma(kv, kreg[i], a);
        }
        g_lds[t * HD + lane] = hsum4(a);
    }

    // dv quarter = v_lane[16wid..16wid+16); R = 0; partial nd2
    v4f dv[4], R[4];
    v4f acc = {0.f, 0.f, 0.f, 0.f};
    #pragma unroll
    for (int i = 0; i < 4; ++i) {
        dv[i] = *(const v4f*)&v_lds[lane * HD + wid * 16 + i * 4];
        R[i]  = (v4f){0.f, 0.f, 0.f, 0.f};
        acc   = __builtin_elementwise_fma(dv[i], dv[i], acc);
    }
    pbuf[0][wid][lane] = hsum4(acc);
    int pp = 1;
    __syncthreads();                       // g_lds + pbuf[0] visible
    float nd2 = ((pbuf[0][0][lane] + pbuf[0][1][lane]) +
                 (pbuf[0][2][lane] + pbuf[0][3][lane]));
    unsigned long long fireset = __ballot(nd2 > thr2);

    // Phase 2: fire loop (R8-verified)
    int chunk = tok_lds[lane];
    #pragma unroll 1
    for (int c = 0; c < NCH; ++c) {
        int nxt = 0;
        if (c + 1 < NCH) nxt = tok_lds[(c + 1) * 64 + lane];
        unsigned long long pend = __ballot((int)((fireset >> chunk) & 1ull));
        while (pend) {
            const int s = __builtin_ctzll(pend);
            const int t = __builtin_amdgcn_readlane(chunk, s);
            const float g   = g_lds[t * HD + lane];
            const float cqt = bcastf(cq, t);
            const v4f gs  = {-g, -g, -g, -g};
            const v4f cqs = {cqt, cqt, cqt, cqt};
            v4f q4 = {0.f, 0.f, 0.f, 0.f};
            #pragma unroll
            for (int i = 0; i < 4; ++i) {
                v4f sve;                           // delta_t quarter (own regs)
                sve.x = bcastf(dv[i].x, t);
                sve.y = bcastf(dv[i].y, t);
                sve.z = bcastf(dv[i].z, t);
                sve.w = bcastf(dv[i].w, t);
                dv[i] = __builtin_elementwise_fma(gs, sve, dv[i]);
                R[i]  = __builtin_elementwise_fma(cqs, sve, R[i]);
                q4    = __builtin_elementwise_fma(dv[i], dv[i], q4);
            }
            pbuf[pp][wid][lane] = hsum4(q4);
            __syncthreads();                       // single barrier per fire
            nd2 = ((pbuf[pp][0][lane] + pbuf[pp][1][lane]) +
                   (pbuf[pp][2][lane] + pbuf[pp][3][lane]));
            pp ^= 1;                               // ping-pong: no 2nd barrier
            fireset = __ballot(nd2 > thr2);
            const unsigned long long above =
                (s >= 63) ? 0ull : (~0ull << (s + 1));
            pend = __ballot((int)((fireset >> chunk) & 1ull)) & above;
        }
        chunk = nxt;
    }

    // read = relu(R): wave w holds components [16wid..16wid+16) in each lane
    if (lane == 0) {
        #pragma unroll
        for (int i = 0; i < 4; ++i) {
            v4f r = R[i];
            r.x = fmaxf(r.x, 0.f); r.y = fmaxf(r.y, 0.f);
            r.z = fmaxf(r.z, 0.f); r.w = fmaxf(r.w, 0.f);
            *(v4f*)&rd_lds[wid * 16 + i * 4] = r;
        }
    }
    __syncthreads();

    // out[b][c] = sum_j rd[j] * wo[j][c] + bo[c]  — wave 0 only (lane = c)
    if (wid == 0) {
        if (bf) {
            float acc2 = __bfloat162float(((const __hip_bfloat16*)bo)[lane]);
            #pragma unroll 8
            for (int j = 0; j < HD; ++j)
                acc2 = fmaf(rd_lds[j],
                    __bfloat162float(((const __hip_bfloat16*)wo)[j * HD + lane]),
                    acc2);
            ((__hip_bfloat16*)out)[b * HD + lane] = __float2bfloat16(acc2);
        } else {
            float acc2 = ((const float*)bo)[lane];
            #pragma unroll 8
            for (int j = 0; j < HD; ++j)
                acc2 = fmaf(rd_lds[j], ((const float*)wo)[j * HD + lane], acc2);
            ((float*)out)[b * HD + lane] = acc2;
        }
    }
}

extern "C" void kernel_launch(void* const* d_in, const int* in_sizes, int n_in,
                              void* d_out, int out_size, void* d_ws, size_t ws_size,
                              hipStream_t stream) {
    const int* x      = (const int*)d_in[0];
    const void* embed = d_in[1];
    const void* w1    = d_in[2];
    const void* b1    = d_in[3];
    const void* w2    = d_in[4];
    const void* b2    = d_in[5];
    const void* ln_g  = d_in[6];
    const void* ln_b  = d_in[7];
    const void* wk    = d_in[8];
    const void* wvp   = d_in[9];
    const void* wq    = d_in[10];
    const void* wo    = d_in[11];
    const void* bo    = d_in[12];

    fused_kernel<<<NB, 256, 0, stream>>>(x, embed, w1, b1, w2, b2, ln_g, ln_b,
                                         wk, wvp, wq, wo, bo, d_out);
}

// Round 14
// 295.513 us; speedup vs baseline: 1.0703x; 1.0387x over previous
//
#include <hip/hip_runtime.h>
#include <hip/hip_bf16.h>

#define HD   64
#define SEQ  2048
#define NB   256
#define TWOH 128
#define NCH  32   // SEQ / 64
#define KS   68   // padded row stride for k/v tables (16B-aligned, 8-way max)

typedef float v4f __attribute__((ext_vector_type(4)));

// ---- DPP wave-total: sum across 64 lanes, broadcast via lane 63 ----
template <int CTRL>
__device__ __forceinline__ float dpp_add(float x) {
    int y = __builtin_amdgcn_update_dpp(0, __builtin_bit_cast(int, x),
                                        CTRL, 0xF, 0xF, true);
    return x + __builtin_bit_cast(float, y);
}

__device__ __forceinline__ float wave_total(float x) {
    x = dpp_add<0x111>(x);   // row_shr:1
    x = dpp_add<0x112>(x);   // row_shr:2
    x = dpp_add<0x114>(x);   // row_shr:4
    x = dpp_add<0x118>(x);   // row_shr:8
    x = dpp_add<0x142>(x);   // row_bcast:15
    x = dpp_add<0x143>(x);   // row_bcast:31 -> lane 63 has full sum
    return __builtin_bit_cast(float,
        __builtin_amdgcn_readlane(__builtin_bit_cast(int, x), 63));
}

__device__ __forceinline__ float bcastf(float v, int l) {
    return __builtin_bit_cast(float,
        __builtin_amdgcn_readlane(__builtin_bit_cast(int, v), l));
}

__device__ __forceinline__ float hsum4(v4f a) {
    return (a.x + a.y) + (a.z + a.w);
}

// f32 data read as bf16 at even 16-bit halves -> huge/NaN values. Wave-level
// (__any over 64 lanes); lane-indexed so all waves get identical results.
__device__ __forceinline__ bool detect_bf16(const void* embed, int lane) {
    const unsigned short* u = (const unsigned short*)embed;
    int bad = 0;
    for (int i = 2 * lane; i < 4096; i += 128) {
        float v = __uint_as_float(((unsigned int)u[i]) << 16);
        if (!(fabsf(v) < 1e4f)) bad = 1;
    }
    return !__any(bad);
}

template <bool BF>
__device__ __forceinline__ float ldf(const void* p, int i) {
    if (BF) return __bfloat162float(((const __hip_bfloat16*)p)[i]);
    return ((const float*)p)[i];
}

// Register-resident encoder: wave `wid` encodes tokens 16wid..16wid+16
// simultaneously (token dim in registers, feature dim in lanes). ALL
// cross-lane broadcasts use v_readlane on the wave's own SIMD — R13 showed
// LDS-based broadcasts serialize 4 waves on the single shared LDS pipe
// (~18 µs). Weights stream from global with next-iteration prefetch; each
// j4 body is ~380 VALU cyc, hiding the ~200 cyc L2 latency. No LDS scratch
// at all (no R4-hazard surface). q computed only for token tl.
template <bool BF>
__device__ void encode_reg(int wid, int lane, int tl, const void* embed,
                           const void* w1, const void* b1, const void* w2,
                           const void* b2, const void* ln_g, const void* ln_b,
                           const void* wk, const void* wvp, const void* wq,
                           float* __restrict__ k_lds, float* __restrict__ v_lds,
                           float* __restrict__ thr2_lds,
                           float* __restrict__ qrow_s) {
    const int tbase = wid * 16;
    float h[16];
    #pragma unroll
    for (int it = 0; it < 16; ++it)
        h[it] = ldf<BF>(embed, (tbase + it) * HD + lane);

    // ---- FFN1: u[it][e] = relu(sum_j h[it][j]*w1[j][e]+b1[e]); e=lane,lane+64
    float u0[16], u1[16];
    #pragma unroll
    for (int it = 0; it < 16; ++it) { u0[it] = 0.f; u1[it] = 0.f; }
    float a0 = ldf<BF>(w1, 0 * TWOH + lane), b0 = ldf<BF>(w1, 0 * TWOH + lane + HD);
    float a1 = ldf<BF>(w1, 1 * TWOH + lane), b1w = ldf<BF>(w1, 1 * TWOH + lane + HD);
    float a2 = ldf<BF>(w1, 2 * TWOH + lane), b2w = ldf<BF>(w1, 2 * TWOH + lane + HD);
    float a3 = ldf<BF>(w1, 3 * TWOH + lane), b3w = ldf<BF>(w1, 3 * TWOH + lane + HD);
    #pragma unroll 1
    for (int j4 = 0; j4 < 16; ++j4) {
        float na0 = 0, nb0 = 0, na1 = 0, nb1 = 0,
              na2 = 0, nb2 = 0, na3 = 0, nb3 = 0;
        if (j4 < 15) {                       // prefetch next 4 rows
            const int j = (j4 + 1) * 4;
            na0 = ldf<BF>(w1, (j + 0) * TWOH + lane);
            nb0 = ldf<BF>(w1, (j + 0) * TWOH + lane + HD);
            na1 = ldf<BF>(w1, (j + 1) * TWOH + lane);
            nb1 = ldf<BF>(w1, (j + 1) * TWOH + lane + HD);
            na2 = ldf<BF>(w1, (j + 2) * TWOH + lane);
            nb2 = ldf<BF>(w1, (j + 2) * TWOH + lane + HD);
            na3 = ldf<BF>(w1, (j + 3) * TWOH + lane);
            nb3 = ldf<BF>(w1, (j + 3) * TWOH + lane + HD);
        }
        const int j = j4 * 4;
        #pragma unroll
        for (int it = 0; it < 16; ++it) {
            const float s0 = bcastf(h[it], j + 0);   // own-SIMD broadcast
            const float s1 = bcastf(h[it], j + 1);
            const float s2 = bcastf(h[it], j + 2);
            const float s3 = bcastf(h[it], j + 3);
            u0[it] = fmaf(s0, a0, u0[it]); u1[it] = fmaf(s0, b0, u1[it]);
            u0[it] = fmaf(s1, a1, u0[it]); u1[it] = fmaf(s1, b1w, u1[it]);
            u0[it] = fmaf(s2, a2, u0[it]); u1[it] = fmaf(s2, b2w, u1[it]);
            u0[it] = fmaf(s3, a3, u0[it]); u1[it] = fmaf(s3, b3w, u1[it]);
        }
        a0 = na0; b0 = nb0; a1 = na1; b1w = nb1;
        a2 = na2; b2w = nb2; a3 = na3; b3w = nb3;
    }
    const float bb0 = ldf<BF>(b1, lane), bb1 = ldf<BF>(b1, lane + HD);
    #pragma unroll
    for (int it = 0; it < 16; ++it) {
        u0[it] = fmaxf(u0[it] + bb0, 0.f);
        u1[it] = fmaxf(u1[it] + bb1, 0.f);
    }

    // ---- FFN2: f[it] = sum_e u[it][e]*w2[e][lane]  (pass A: u0, pass B: u1)
    float f[16];
    #pragma unroll
    for (int it = 0; it < 16; ++it) f[it] = 0.f;
    {   // pass A: e = 0..63 from u0
        float w0 = ldf<BF>(w2, 0 * HD + lane), w1v = ldf<BF>(w2, 1 * HD + lane);
        float w2v = ldf<BF>(w2, 2 * HD + lane), w3 = ldf<BF>(w2, 3 * HD + lane);
        #pragma unroll 1
        for (int e4 = 0; e4 < 16; ++e4) {
            float n0 = 0, n1 = 0, n2 = 0, n3 = 0;
            if (e4 < 15) {
                const int e = (e4 + 1) * 4;
                n0 = ldf<BF>(w2, (e + 0) * HD + lane);
                n1 = ldf<BF>(w2, (e + 1) * HD + lane);
                n2 = ldf<BF>(w2, (e + 2) * HD + lane);
                n3 = ldf<BF>(w2, (e + 3) * HD + lane);
            }
            const int e = e4 * 4;
            #pragma unroll
            for (int it = 0; it < 16; ++it) {
                f[it] = fmaf(bcastf(u0[it], e + 0), w0, f[it]);
                f[it] = fmaf(bcastf(u0[it], e + 1), w1v, f[it]);
                f[it] = fmaf(bcastf(u0[it], e + 2), w2v, f[it]);
                f[it] = fmaf(bcastf(u0[it], e + 3), w3, f[it]);
            }
            w0 = n0; w1v = n1; w2v = n2; w3 = n3;
        }
    }
    {   // pass B: e = 64..127 from u1
        float w0 = ldf<BF>(w2, 64 * HD + lane), w1v = ldf<BF>(w2, 65 * HD + lane);
        float w2v = ldf<BF>(w2, 66 * HD + lane), w3 = ldf<BF>(w2, 67 * HD + lane);
        #pragma unroll 1
        for (int e4 = 0; e4 < 16; ++e4) {
            float n0 = 0, n1 = 0, n2 = 0, n3 = 0;
            if (e4 < 15) {
                const int e = HD + (e4 + 1) * 4;
                n0 = ldf<BF>(w2, (e + 0) * HD + lane);
                n1 = ldf<BF>(w2, (e + 1) * HD + lane);
                n2 = ldf<BF>(w2, (e + 2) * HD + lane);
                n3 = ldf<BF>(w2, (e + 3) * HD + lane);
            }
            const int e = e4 * 4;
            #pragma unroll
            for (int it = 0; it < 16; ++it) {
                f[it] = fmaf(bcastf(u1[it], e + 0), w0, f[it]);
                f[it] = fmaf(bcastf(u1[it], e + 1), w1v, f[it]);
                f[it] = fmaf(bcastf(u1[it], e + 2), w2v, f[it]);
                f[it] = fmaf(bcastf(u1[it], e + 3), w3, f[it]);
            }
            w0 = n0; w1v = n1; w2v = n2; w3 = n3;
        }
    }

    // ---- LayerNorm per token (eps 1e-5) ----
    const float b2v = ldf<BF>(b2, lane);
    const float lg = ldf<BF>(ln_g, lane), lb = ldf<BF>(ln_b, lane);
    float hn[16];
    #pragma unroll 1
    for (int it = 0; it < 16; ++it) {
        float y = h[it] + f[it] + b2v;
        float mu  = wave_total(y) * 0.015625f;
        float dvv = y - mu;
        float var = wave_total(dvv * dvv) * 0.015625f;
        hn[it] = fmaf(dvv * (1.f / sqrtf(var + 1e-5f)), lg, lb);
    }

    // ---- k/v projections ----
    float k[16], v[16];
    #pragma unroll
    for (int it = 0; it < 16; ++it) { k[it] = 0.f; v[it] = 0.f; }
    float ka = ldf<BF>(wk, 0 * HD + lane), kb = ldf<BF>(wk, 1 * HD + lane);
    float kc = ldf<BF>(wk, 2 * HD + lane), kd = ldf<BF>(wk, 3 * HD + lane);
    float va = ldf<BF>(wvp, 0 * HD + lane), vb = ldf<BF>(wvp, 1 * HD + lane);
    float vc = ldf<BF>(wvp, 2 * HD + lane), vd = ldf<BF>(wvp, 3 * HD + lane);
    #pragma unroll 1
    for (int j4 = 0; j4 < 16; ++j4) {
        float nka = 0, nkb = 0, nkc = 0, nkd = 0,
              nva = 0, nvb = 0, nvc = 0, nvd = 0;
        if (j4 < 15) {
            const int j = (j4 + 1) * 4;
            nka = ldf<BF>(wk, (j + 0) * HD + lane);
            nkb = ldf<BF>(wk, (j + 1) * HD + lane);
            nkc = ldf<BF>(wk, (j + 2) * HD + lane);
            nkd = ldf<BF>(wk, (j + 3) * HD + lane);
            nva = ldf<BF>(wvp, (j + 0) * HD + lane);
            nvb = ldf<BF>(wvp, (j + 1) * HD + lane);
            nvc = ldf<BF>(wvp, (j + 2) * HD + lane);
            nvd = ldf<BF>(wvp, (j + 3) * HD + lane);
        }
        const int j = j4 * 4;
        #pragma unroll
        for (int it = 0; it < 16; ++it) {
            const float s0 = bcastf(hn[it], j + 0);
            const float s1 = bcastf(hn[it], j + 1);
            const float s2 = bcastf(hn[it], j + 2);
            const float s3 = bcastf(hn[it], j + 3);
            k[it] = fmaf(s0, ka, k[it]); v[it] = fmaf(s0, va, v[it]);
            k[it] = fmaf(s1, kb, k[it]); v[it] = fmaf(s1, vb, v[it]);
            k[it] = fmaf(s2, kc, k[it]); v[it] = fmaf(s2, vc, v[it]);
            k[it] = fmaf(s3, kd, k[it]); v[it] = fmaf(s3, vd, v[it]);
        }
        ka = nka; kb = nkb; kc = nkc; kd = nkd;
        va = nva; vb = nvb; vc = nvc; vd = nvd;
    }

    // normalize + write tables (stride KS=68)
    #pragma unroll 1
    for (int it = 0; it < 16; ++it) {
        const int t = tbase + it;
        float nk = sqrtf(wave_total(k[it] * k[it]));
        float kn = k[it] / fmaxf(nk, 1e-12f);       // k / max(||k||, NORM_EPS)
        float nv2 = wave_total(v[it] * v[it]);
        k_lds[t * KS + lane] = kn;
        v_lds[t * KS + lane] = v[it];
        if (lane == 0) thr2_lds[t] = 0.16f * nv2;   // (0.4*||v||)^2
    }

    // q only for token tl (wave-uniform branch)
    if (tl >= tbase && tl < tbase + 16) {
        const int it = tl - tbase;
        float q = 0.f;
        #pragma unroll
        for (int j4 = 0; j4 < 16; ++j4) {
            const int j = j4 * 4;
            q = fmaf(bcastf(hn[it], j + 0), ldf<BF>(wq, (j + 0) * HD + lane), q);
            q = fmaf(bcastf(hn[it], j + 1), ldf<BF>(wq, (j + 1) * HD + lane), q);
            q = fmaf(bcastf(hn[it], j + 2), ldf<BF>(wq, (j + 2) * HD + lane), q);
            q = fmaf(bcastf(hn[it], j + 3), ldf<BF>(wq, (j + 3) * HD + lane), q);
        }
        qrow_s[lane] = q;
    }
}

// Single plain launch: 256 blocks x 4 waves (one per SIMD).
// Phase 1: register-resident encoder (readlane broadcasts, global weights).
// Phase 2: R8-verified fire loop — wave w owns components [16w,16w+16) of
// every token's residual dv; fires broadcast delta quarters from own-lane
// registers (16 readlanes), 12 pk_fma, combine ||dv||^2 partials via
// ping-pong LDS with ONE barrier per fire.
__global__ __launch_bounds__(256, 1) void fused_kernel(
    const int* __restrict__ x, const void* embed, const void* w1,
    const void* b1, const void* w2, const void* b2, const void* ln_g,
    const void* ln_b, const void* wk, const void* wvp, const void* wq,
    const void* wo, const void* bo, void* __restrict__ out) {
    const int b = blockIdx.x, tid = threadIdx.x;
    const int wid = tid >> 6, lane = tid & 63;
    __shared__ __align__(16) float k_lds[64 * KS];
    __shared__ __align__(16) float v_lds[64 * KS];
    __shared__ __align__(16) float g_lds[4096];
    __shared__ int   tok_lds[SEQ];
    __shared__ float thr2_lds[64];
    __shared__ float qrow_s[64];
    __shared__ float pbuf[2][4][64];     // ping-pong nd2 partials
    __shared__ __align__(16) float rd_lds[64];

    // stage token stream (coalesced over 256 threads)
    const int* xr = x + b * SEQ;
    #pragma unroll
    for (int c = 0; c < 8; ++c) tok_lds[c * 256 + tid] = xr[c * 256 + tid];
    const int tl = xr[SEQ - 1];

    // Phase 1: encoder
    const bool bf = detect_bf16(embed, lane);
    if (bf)
        encode_reg<true>(wid, lane, tl, embed, w1, b1, w2, b2, ln_g, ln_b,
                         wk, wvp, wq, k_lds, v_lds, thr2_lds, qrow_s);
    else
        encode_reg<false>(wid, lane, tl, embed, w1, b1, w2, b2, ln_g, ln_b,
                          wk, wvp, wq, k_lds, v_lds, thr2_lds, qrow_s);
    __syncthreads();                     // k/v/thr2/qrow visible

    const float thr2 = thr2_lds[lane];

    // k_lane full row into registers (stride-68 -> 8-way max conflicts)
    v4f kreg[16];
    #pragma unroll
    for (int i = 0; i < 16; ++i)
        kreg[i] = *(const v4f*)&k_lds[lane * KS + i * 4];

    // cq_lane = k_lane . q_tl  (qrow_s uniform reads -> broadcast)
    v4f cacc = {0.f, 0.f, 0.f, 0.f};
    #pragma unroll
    for (int i = 0; i < 16; ++i) {
        const v4f qv = *(const v4f*)&qrow_s[i * 4];
        cacc = __builtin_elementwise_fma(qv, kreg[i], cacc);
    }
    const float cq = hsum4(cacc);

    // G build: wave w computes rows [16w,16w+16): G[t][lane] = k_t . k_lane
    #pragma unroll 1
    for (int t0 = 0; t0 < 16; ++t0) {
        const int t = wid * 16 + t0;
        const float* kt = &k_lds[t * KS];    // uniform -> LDS broadcast
        v4f a = {0.f, 0.f, 0.f, 0.f};
        #pragma unroll
        for (int i = 0; i < 16; ++i) {
            const v4f kv = *(const v4f*)&kt[i * 4];
            a = __builtin_elementwise_fma(kv, kreg[i], a);
        }
        g_lds[t * HD + lane] = hsum4(a);
    }

    // dv quarter = v_lane[16wid..16wid+16); R = 0; partial nd2
    v4f dv[4], R[4];
    v4f acc = {0.f, 0.f, 0.f, 0.f};
    #pragma unroll
    for (int i = 0; i < 4; ++i) {
        dv[i] = *(const v4f*)&v_lds[lane * KS + wid * 16 + i * 4];
        R[i]  = (v4f){0.f, 0.f, 0.f, 0.f};
        acc   = __builtin_elementwise_fma(dv[i], dv[i], acc);
    }
    pbuf[0][wid][lane] = hsum4(acc);
    int pp = 1;
    __syncthreads();                       // g_lds + pbuf[0] visible
    float nd2 = ((pbuf[0][0][lane] + pbuf[0][1][lane]) +
                 (pbuf[0][2][lane] + pbuf[0][3][lane]));
    unsigned long long fireset = __ballot(nd2 > thr2);

    // Phase 2: fire loop (R8-verified)
    int chunk = tok_lds[lane];
    #pragma unroll 1
    for (int c = 0; c < NCH; ++c) {
        int nxt = 0;
        if (c + 1 < NCH) nxt = tok_lds[(c + 1) * 64 + lane];
        unsigned long long pend = __ballot((int)((fireset >> chunk) & 1ull));
        while (pend) {
            const int s = __builtin_ctzll(pend);
            const int t = __builtin_amdgcn_readlane(chunk, s);
            const float g   = g_lds[t * HD + lane];
            const float cqt = bcastf(cq, t);
            const v4f gs  = {-g, -g, -g, -g};
            const v4f cqs = {cqt, cqt, cqt, cqt};
            v4f q4 = {0.f, 0.f, 0.f, 0.f};
            #pragma unroll
            for (int i = 0; i < 4; ++i) {
                v4f sve;                           // delta_t quarter (own regs)
                sve.x = bcastf(dv[i].x, t);
                sve.y = bcastf(dv[i].y, t);
                sve.z = bcastf(dv[i].z, t);
                sve.w = bcastf(dv[i].w, t);
                dv[i] = __builtin_elementwise_fma(gs, sve, dv[i]);
                R[i]  = __builtin_elementwise_fma(cqs, sve, R[i]);
                q4    = __builtin_elementwise_fma(dv[i], dv[i], q4);
            }
            pbuf[pp][wid][lane] = hsum4(q4);
            __syncthreads();                       // single barrier per fire
            nd2 = ((pbuf[pp][0][lane] + pbuf[pp][1][lane]) +
                   (pbuf[pp][2][lane] + pbuf[pp][3][lane]));
            pp ^= 1;                               // ping-pong: no 2nd barrier
            fireset = __ballot(nd2 > thr2);
            const unsigned long long above =
                (s >= 63) ? 0ull : (~0ull << (s + 1));
            pend = __ballot((int)((fireset >> chunk) & 1ull)) & above;
        }
        chunk = nxt;
    }

    // read = relu(R): wave w holds components [16wid..16wid+16) in each lane
    if (lane == 0) {
        #pragma unroll
        for (int i = 0; i < 4; ++i) {
            v4f r = R[i];
            r.x = fmaxf(r.x, 0.f); r.y = fmaxf(r.y, 0.f);
            r.z = fmaxf(r.z, 0.f); r.w = fmaxf(r.w, 0.f);
            *(v4f*)&rd_lds[wid * 16 + i * 4] = r;
        }
    }
    __syncthreads();

    // out[b][c] = sum_j rd[j] * wo[j][c] + bo[c]  — wave 0 only (lane = c)
    if (wid == 0) {
        if (bf) {
            float acc2 = __bfloat162float(((const __hip_bfloat16*)bo)[lane]);
            #pragma unroll 8
            for (int j = 0; j < HD; ++j)
                acc2 = fmaf(rd_lds[j],
                    __bfloat162float(((const __hip_bfloat16*)wo)[j * HD + lane]),
                    acc2);
            ((__hip_bfloat16*)out)[b * HD + lane] = __float2bfloat16(acc2);
        } else {
            float acc2 = ((const float*)bo)[lane];
            #pragma unroll 8
            for (int j = 0; j < HD; ++j)
                acc2 = fmaf(rd_lds[j], ((const float*)wo)[j * HD + lane], acc2);
            ((float*)out)[b * HD + lane] = acc2;
        }
    }
}

extern "C" void kernel_launch(void* const* d_in, const int* in_sizes, int n_in,
                              void* d_out, int out_size, void* d_ws, size_t ws_size,
                              hipStream_t stream) {
    const int* x      = (const int*)d_in[0];
    const void* embed = d_in[1];
    const void* w1    = d_in[2];
    const void* b1    = d_in[3];
    const void* w2    = d_in[4];
    const void* b2    = d_in[5];
    const void* ln_g  = d_in[6];
    const void* ln_b  = d_in[7];
    const void* wk    = d_in[8];
    const void* wvp   = d_in[9];
    const void* wq    = d_in[10];
    const void* wo    = d_in[11];
    const void* bo    = d_in[12];

    fused_kernel<<<NB, 256, 0, stream>>>(x, embed, w1, b1, w2, b2, ln_g, ln_b,
                                         wk, wvp, wq, wo, bo, d_out);
}